// Round 6
// baseline (601.584 us; speedup 1.0000x reference)
//
#include <hip/hip_runtime.h>
#include <hip/hip_bf16.h>

typedef _Float16 h8 __attribute__((ext_vector_type(8)));
typedef __bf16   b8 __attribute__((ext_vector_type(8)));
typedef float    f4 __attribute__((ext_vector_type(4)));

#define B_    4
#define S_    4096
#define D_    512
#define ROWS_ (B_ * S_)          // 16384
#define NQKV_ 1536
#define BR    64                 // q-rows per block
#define BC    32                 // keys per iteration
#define KP    520                // K LDS pitch (f16)
#define PP    40                 // P LDS pitch (bf16)
#define NIT   (S_ / BC)          // 128
#define KTILE (BC * KP)
#define MSH   (30.0f * 1.4426950408889634f)   // fixed softmax shift (log2 units)
#define L2E   1.4426950408889634f

// async global->LDS, 16B per lane; dst is wave-uniform base (+lane*16 implied)
__device__ __forceinline__ void gl_lds16(const void* src, void* dst) {
    __builtin_amdgcn_global_load_lds(
        (const __attribute__((address_space(1))) unsigned int*)src,
        (__attribute__((address_space(3))) unsigned int*)dst, 16, 0, 0);
}

// ---------------------------------------------------------------- convert ---
__global__ __launch_bounds__(256) void convert_all(
    const float* __restrict__ x,
    const float* __restrict__ Wq, const float* __restrict__ Wk, const float* __restrict__ Wv,
    const float* __restrict__ bq, const float* __restrict__ bk, const float* __restrict__ bv,
    const float* __restrict__ Wo,
    _Float16* __restrict__ xh, _Float16* __restrict__ wqkvT, _Float16* __restrict__ woT,
    float* __restrict__ bqkv)
{
    long i0 = (long)blockIdx.x * blockDim.x + threadIdx.x;
    long stride = (long)gridDim.x * blockDim.x;
    const long NX  = (long)ROWS_ * D_;
    const long NW  = (long)D_ * NQKV_;
    const long NWO = (long)D_ * D_;

    for (long i = i0; i < NX; i += stride) xh[i] = (_Float16)x[i];

    for (long i = i0; i < NW; i += stride) {
        long n = i >> 9, k = i & 511;
        long which = n >> 9, nn = n & 511;
        const float* W = (which == 0) ? Wq : (which == 1) ? Wk : Wv;
        wqkvT[i] = (_Float16)W[k * 512 + nn];
    }
    for (long i = i0; i < NWO; i += stride) {
        long n = i >> 9, k = i & 511;
        woT[i] = (_Float16)Wo[k * 512 + n];
    }
    for (long i = i0; i < NQKV_; i += stride) {
        long which = i >> 9, nn = i & 511;
        const float* bb = (which == 0) ? bq : (which == 1) ? bk : bv;
        bqkv[i] = bb[nn];
    }
}

// ------------------------------------------------------------------- GEMM ---
#define GP 40
template <bool OUT_F16>
__global__ __launch_bounds__(256) void gemm_bt(
    const _Float16* __restrict__ A, const _Float16* __restrict__ BT,
    const float* __restrict__ bias, void* __restrict__ Cout,
    int M, int N, int K)
{
    __shared__ _Float16 As[128 * GP];
    __shared__ _Float16 Bs[128 * GP];

    int tid = threadIdx.x;
    int w = tid >> 6, lane = tid & 63, quad = lane >> 4, l16 = lane & 15;
    long row0 = (long)blockIdx.x * 128, col0 = (long)blockIdx.y * 128;
    int wr = (w >> 1) * 64, wc = (w & 1) * 64;

    f4 acc[4][4];
    for (int i = 0; i < 4; i++)
        for (int j = 0; j < 4; j++) acc[i][j] = (f4){0.f, 0.f, 0.f, 0.f};

    int sr = tid >> 1, sc = (tid & 1) * 16;
    for (int k0 = 0; k0 < K; k0 += 32) {
        __syncthreads();
        {
            const h8* ga = (const h8*)(A  + (row0 + sr) * K + k0 + sc);
            const h8* gb = (const h8*)(BT + (col0 + sr) * K + k0 + sc);
            *(h8*)(As + sr * GP + sc)     = ga[0];
            *(h8*)(As + sr * GP + sc + 8) = ga[1];
            *(h8*)(Bs + sr * GP + sc)     = gb[0];
            *(h8*)(Bs + sr * GP + sc + 8) = gb[1];
        }
        __syncthreads();
        h8 af[4], bf[4];
        for (int i = 0; i < 4; i++) af[i] = *(const h8*)(As + (wr + i * 16 + l16) * GP + quad * 8);
        for (int j = 0; j < 4; j++) bf[j] = *(const h8*)(Bs + (wc + j * 16 + l16) * GP + quad * 8);
        for (int i = 0; i < 4; i++)
            for (int j = 0; j < 4; j++)
                acc[i][j] = __builtin_amdgcn_mfma_f32_16x16x32_f16(af[i], bf[j], acc[i][j], 0, 0, 0);
    }
    for (int i = 0; i < 4; i++)
        for (int j = 0; j < 4; j++)
            for (int r = 0; r < 4; r++) {
                long row = row0 + wr + i * 16 + quad * 4 + r;
                long col = col0 + wc + j * 16 + l16;
                float v = acc[i][j][r] + bias[col];
                if (OUT_F16) ((_Float16*)Cout)[row * N + col] = (_Float16)v;
                else         ((float*)Cout)[row * N + col]    = v;
            }
}

// ---------------------------------------------------------------- pack V ---
// vP fragment-major layout: for batch b, key-tile kt (32 keys), d-tile dt
// (16 d), the 16x32 tile is stored as 512 contiguous bf16:
//   vP[(((b*128)+kt)*32+dt)*512 + (q*16+l)*8 + k3] = V[b][kt*32+q*8+k3][dt*16+l]
// so an MFMA B-fragment load is lane*16B off a wave-uniform base.
__global__ __launch_bounds__(256) void pack_v(const _Float16* __restrict__ qkv,
                                              __bf16* __restrict__ vP)
{
    __shared__ _Float16 T[32 * 520];
    int kt = blockIdx.x, b = blockIdx.y;
    int t = threadIdx.x;

    // coalesced load: 32 keys x 512 d (f16) from qkv[.][1024+..]
    const _Float16* src = qkv + ((long)b * S_ + kt * 32 + (t >> 3)) * NQKV_ + 1024;
#pragma unroll
    for (int i = 0; i < 8; i++) {
        int c = (t & 7) + i * 8;                     // chunk 0..63 within row
        *(h8*)(T + (t >> 3) * 520 + c * 8) = *(const h8*)(src + c * 8);
    }
    __syncthreads();

    // coalesced store: 2048 chunks of 8 bf16; chunk c -> dt=c>>6, q=(c>>4)&3, l=c&15
    __bf16* dst = vP + (((long)b * 128 + kt) * 32) * 512;
#pragma unroll
    for (int i = 0; i < 8; i++) {
        int c = t + i * 256;
        int dt = c >> 6, q = (c >> 4) & 3, l = c & 15;
        b8 out;
#pragma unroll
        for (int k3 = 0; k3 < 8; k3++)
            out[k3] = (__bf16)(float)T[(q * 8 + k3) * 520 + dt * 16 + l];
        *(b8*)(dst + (long)c * 8) = out;
    }
}

// -------------------------------------------------------- flash attention ---
// BR=64, BC=32, 8 waves (512 thr), 256 blocks (1/CU), XCD batch affinity.
// SPLIT kb SOURCING: the LDS pipe was ~80% busy, dominated by 4x-redundant
// kb reads (4 waves share each K-half, each re-reading 16KB/iter).  Odd waves
// (1,3,5,7) now read K fragments DIRECTLY FROM GLOBAL (L2-hot via the XCD
// swizzle; same lines the DMA pulls) into a rotating 16xh8 register buffer,
// prefetched one tile ahead (use kbuf[ks] then overwrite with kt+1's frag).
// Even waves keep the LDS path.  LDS kb traffic halves (128->64 KB/iter);
// global path rises to ~51 B/cy/CU -- both pipes under their ceilings.
// vmcnt bookkeeping (region-count based, order-robust):
//   odd waves issue 24 vmem ops/region (4 V + 4 DMA + 16 kb) -> vmcnt(24)
//   at the barrier (20/16 at the two tail iters); this also forces all
//   pre-region ops (incl. their DMA(kt+1) share) retired => LDS visibility.
//   even waves: vmcnt(8)/(4) as before.  kb prefetch is unconditional; at
//   kt=127 it reads past the K panel into the mapped vP region (never used).
__global__ __launch_bounds__(512, 2) void attn_kernel(const _Float16* __restrict__ qkv,
                                                      const __bf16* __restrict__ vP,
                                                      _Float16* __restrict__ yb)
{
    __shared__ _Float16 Ks[4 * KTILE];      // 133120 B
    __shared__ __bf16   Ps[2 * BR * PP];    // 10240 B
    __shared__ float    lpart[2][BR];       // 512 B

    const int tid = threadIdx.x;
    const int w = tid >> 6, lane = tid & 63, quad = lane >> 4, l16 = lane & 15;
    const int rs = (w & 3) * 16;            // score row strip
    const int kh = w >> 2;                  // key half (0/1)
    const bool gk = (w & 1);                // global-K wave?

    // ---- batch->XCD affinity swizzle (bijective over 256 blocks)
    const int bid = blockIdx.x;
    const int xcd = bid & 7;
    const int b = xcd >> 1;
    const long q0 = (long)((xcd & 1) * 32 + (bid >> 3)) * BR;
    const long rowBase = (long)b * S_;

    const _Float16* kbase = qkv + rowBase * NQKV_ + 512;
    const __bf16* vpbase = vP + ((long)b * 128 * 32 + w * 4) * 512 + lane * 8;
    // per-lane global K-fragment base: row kh*16+l16, col quad*8 (f16)
    const _Float16* kgbase = kbase + (long)(kh * 16 + l16) * NQKV_ + quad * 8;

    // ---- Q fragments FIRST (oldest vmem; drained at prologue barrier)
    h8 Qf[16];
    {
        const _Float16* qrow = qkv + (rowBase + q0 + rs + l16) * NQKV_;
#pragma unroll
        for (int ks = 0; ks < 16; ks++)
            Qf[ks] = *(const h8*)(qrow + ks * 32 + quad * 8);
    }

    // ---- prologue: DMA K tiles 0,1; V(0) into vA; odd waves: kb(0) to regs
#pragma unroll
    for (int t = 0; t < 2; t++)
#pragma unroll
        for (int i = 0; i < 4; i++) {
            int r = w * 4 + i;
            gl_lds16(kbase + (long)(t * BC + r) * NQKV_ + lane * 8,
                     Ks + t * KTILE + r * KP);
        }
    b8 vA[4], vB[4];
#pragma unroll
    for (int ct = 0; ct < 4; ct++)
        vA[ct] = *(const b8*)(vpbase + ct * 512);

    h8 kbuf[16];
    if (gk) {
#pragma unroll
        for (int ks = 0; ks < 16; ks++)
            kbuf[ks] = *(const h8*)(kgbase + ks * 32);
    }

    f4 O[4][4];
#pragma unroll
    for (int rt = 0; rt < 4; rt++)
#pragma unroll
        for (int ct = 0; ct < 4; ct++) O[rt][ct] = (f4){0.f, 0.f, 0.f, 0.f};
    float lo[4] = {0.f, 0.f, 0.f, 0.f};

    __builtin_amdgcn_sched_barrier(0);
    if (gk) asm volatile("s_waitcnt vmcnt(24)");  // drains Qf+DMA(0); DMA(1)+vA+kb0 fly
    else    asm volatile("s_waitcnt vmcnt(8)");   // drains Qf+DMA(0); DMA(1)+vA fly
    __builtin_amdgcn_s_barrier();
    __builtin_amdgcn_sched_barrier(0);

#define ATTN_BODY(KT, VUSE, VLOAD)                                              \
  {                                                                             \
    const int kt_ = (KT);                                                       \
    /* V(kt+1) loads, then DMA(kt+2); odd waves add 16 kb(kt+1) loads inside   \
       the score loop -> 24 region vmem ops for odd, 8 for even. */            \
    if (kt_ + 1 < NIT) {                                                        \
      const __bf16* vs = vpbase + (long)(kt_ + 1) * (32 * 512);                 \
      _Pragma("unroll")                                                         \
      for (int ct = 0; ct < 4; ct++)                                            \
        VLOAD[ct] = *(const b8*)(vs + ct * 512);                                \
    }                                                                           \
    if (kt_ + 2 < NIT) {                                                        \
      const _Float16* kn = kbase + (long)(kt_ + 2) * BC * NQKV_;                \
      _Float16* kd = Ks + ((kt_ + 2) & 3) * KTILE;                              \
      _Pragma("unroll")                                                         \
      for (int i = 0; i < 4; i++) {                                             \
        int r = w * 4 + i;                                                      \
        gl_lds16(kn + (long)r * NQKV_ + lane * 8, kd + r * KP);                 \
      }                                                                         \
    }                                                                           \
    /* scores: 16x16 tile, K=512, two independent 8-deep chains */              \
    f4 S0 = (f4){0.f, 0.f, 0.f, 0.f};                                           \
    f4 S1 = (f4){0.f, 0.f, 0.f, 0.f};                                           \
    if (gk) {                                                                   \
      /* consume kbuf (tile kt), overwrite with tile kt+1 fragments */          \
      const _Float16* kg = kgbase + (long)(kt_ + 1) * BC * NQKV_;               \
      _Pragma("unroll")                                                         \
      for (int ks = 0; ks < 8; ks++) {                                          \
        S0 = __builtin_amdgcn_mfma_f32_16x16x32_f16(Qf[ks],     kbuf[ks],     S0, 0, 0, 0); \
        S1 = __builtin_amdgcn_mfma_f32_16x16x32_f16(Qf[ks + 8], kbuf[ks + 8], S1, 0, 0, 0); \
        kbuf[ks]     = *(const h8*)(kg + ks * 32);                              \
        kbuf[ks + 8] = *(const h8*)(kg + (ks + 8) * 32);                        \
      }                                                                         \
    } else {                                                                    \
      const _Float16* krow = Ks + (kt_ & 3) * KTILE + (kh * 16 + l16) * KP + quad * 8; \
      _Pragma("unroll")                                                         \
      for (int ks = 0; ks < 8; ks++) {                                          \
        h8 kb0 = *(const h8*)(krow + ks * 32);                                  \
        h8 kb1 = *(const h8*)(krow + (ks + 8) * 32);                            \
        S0 = __builtin_amdgcn_mfma_f32_16x16x32_f16(Qf[ks],     kb0, S0, 0, 0, 0); \
        S1 = __builtin_amdgcn_mfma_f32_16x16x32_f16(Qf[ks + 8], kb1, S1, 0, 0, 0); \
      }                                                                         \
    }                                                                           \
    __bf16* ps = Ps + (kt_ & 1) * (BR * PP);                                    \
    _Pragma("unroll")                                                           \
    for (int r = 0; r < 4; r++) {                                               \
      float p = exp2f((S0[r] + S1[r]) * L2E - MSH);                             \
      __bf16 pb = (__bf16)p;                                                    \
      ps[(rs + quad * 4 + r) * PP + kh * 16 + l16] = pb;                        \
      lo[r] += (float)pb;                                                       \
    }                                                                           \
    __builtin_amdgcn_sched_barrier(0);                                          \
    if (gk) {                                                                   \
      if (kt_ < NIT - 2)       asm volatile("s_waitcnt vmcnt(24)");             \
      else if (kt_ == NIT - 2) asm volatile("s_waitcnt vmcnt(20)");             \
      else                     asm volatile("s_waitcnt vmcnt(16)");             \
    } else {                                                                    \
      if (kt_ < NIT - 2)       asm volatile("s_waitcnt vmcnt(8)");              \
      else if (kt_ == NIT - 2) asm volatile("s_waitcnt vmcnt(4)");              \
    }                                                                           \
    asm volatile("s_waitcnt lgkmcnt(0)");                                       \
    __builtin_amdgcn_s_barrier();                                               \
    __builtin_amdgcn_sched_barrier(0);                                          \
    /* PV: A = P rows rt*16+l16 (K=32) from LDS, B = V frags from regs */       \
    b8 pa[4];                                                                   \
    _Pragma("unroll")                                                           \
    for (int rt = 0; rt < 4; rt++)                                              \
      pa[rt] = *(const b8*)(ps + (rt * 16 + l16) * PP + quad * 8);              \
    _Pragma("unroll")                                                           \
    for (int ct = 0; ct < 4; ct++)                                              \
      _Pragma("unroll")                                                         \
      for (int rt = 0; rt < 4; rt++)                                            \
        O[rt][ct] = __builtin_amdgcn_mfma_f32_16x16x32_bf16(pa[rt], VUSE[ct], O[rt][ct], 0, 0, 0); \
  }

    for (int kt = 0; kt < NIT; kt += 2) {
        ATTN_BODY(kt,     vA, vB);
        ATTN_BODY(kt + 1, vB, vA);
    }
#undef ATTN_BODY

    // ---- epilogue: reduce l over the 16 key-columns, publish per half
#pragma unroll
    for (int r = 0; r < 4; r++)
#pragma unroll
        for (int m = 1; m < 16; m <<= 1) lo[r] += __shfl_xor(lo[r], m, 16);
    if (l16 == 0)
        for (int r = 0; r < 4; r++) lpart[kh][rs + quad * 4 + r] = lo[r];
    __syncthreads();

    for (int rt = 0; rt < 4; rt++) {
        f4 l0 = *(const f4*)(&lpart[0][rt * 16 + quad * 4]);
        f4 l1 = *(const f4*)(&lpart[1][rt * 16 + quad * 4]);
        float li[4];
        for (int r = 0; r < 4; r++) li[r] = 1.f / (l0[r] + l1[r]);
        for (int ct = 0; ct < 4; ct++)
            for (int r = 0; r < 4; r++) {
                long row = rowBase + q0 + rt * 16 + quad * 4 + r;
                long col = w * 64 + ct * 16 + l16;
                yb[row * 512 + col] = (_Float16)(O[rt][ct][r] * li[r]);
            }
    }
}

// ----------------------------------------------------------------- launch ---
extern "C" void kernel_launch(void* const* d_in, const int* in_sizes, int n_in,
                              void* d_out, int out_size, void* d_ws, size_t ws_size,
                              hipStream_t stream)
{
    const float* x  = (const float*)d_in[0];
    const float* Wq = (const float*)d_in[1];
    const float* bq = (const float*)d_in[2];
    const float* Wk = (const float*)d_in[3];
    const float* bk = (const float*)d_in[4];
    const float* Wv = (const float*)d_in[5];
    const float* bv = (const float*)d_in[6];
    const float* Wo = (const float*)d_in[7];
    const float* bo = (const float*)d_in[8];
    float* out = (float*)d_out;

    char* ws = (char*)d_ws;
    _Float16* xh    = (_Float16*)(ws);                  // 16 MB
    _Float16* qkv   = (_Float16*)(ws + 16777216);       // 48 MB  [16384][1536]
    __bf16*   vP    = (__bf16*)(ws + 67108864);         // 16 MB  packed V
    _Float16* yb    = (_Float16*)(ws + 83886080);       // 16 MB  [16384][512]
    _Float16* wqkvT = (_Float16*)(ws + 100663296);      // 1.5 MB
    _Float16* woT   = (_Float16*)(ws + 102236160);      // 0.5 MB
    float*    bqkv  = (float*)(ws + 102760448);         // 6 KB

    convert_all<<<2048, 256, 0, stream>>>(x, Wq, Wk, Wv, bq, bk, bv, Wo,
                                          xh, wqkvT, woT, bqkv);

    dim3 g1(128, 12);
    gemm_bt<true><<<g1, 256, 0, stream>>>(xh, wqkvT, bqkv, qkv, ROWS_, NQKV_, D_);

    dim3 gp(128, 4);
    pack_v<<<gp, 256, 0, stream>>>(qkv, vP);

    attn_kernel<<<256, 512, 0, stream>>>(qkv, vP, yb);

    dim3 g2(128, 4);
    gemm_bt<false><<<g2, 256, 0, stream>>>(yb, woT, bo, out, ROWS_, D_, D_);
}

// Round 7
// 320.893 us; speedup vs baseline: 1.8747x; 1.8747x over previous
//
#include <hip/hip_runtime.h>
#include <hip/hip_bf16.h>

typedef _Float16 h8 __attribute__((ext_vector_type(8)));
typedef __bf16   b8 __attribute__((ext_vector_type(8)));
typedef float    f4 __attribute__((ext_vector_type(4)));

#define B_    4
#define S_    4096
#define D_    512
#define ROWS_ (B_ * S_)          // 16384
#define NQKV_ 1536
#define BR    64                 // q-rows per block
#define BC    32                 // keys per iteration
#define KP    520                // K LDS pitch (f16)
#define PP    40                 // P LDS pitch (bf16)
#define NIT   (S_ / BC)          // 128
#define KTILE (BC * KP)
#define MSH   (30.0f * 1.4426950408889634f)   // fixed softmax shift (log2 units)
#define L2E   1.4426950408889634f

// async global->LDS, 16B per lane; dst is wave-uniform base (+lane*16 implied)
__device__ __forceinline__ void gl_lds16(const void* src, void* dst) {
    __builtin_amdgcn_global_load_lds(
        (const __attribute__((address_space(1))) unsigned int*)src,
        (__attribute__((address_space(3))) unsigned int*)dst, 16, 0, 0);
}

// ---------------------------------------------------------------- convert ---
__global__ __launch_bounds__(256) void convert_all(
    const float* __restrict__ x,
    const float* __restrict__ Wq, const float* __restrict__ Wk, const float* __restrict__ Wv,
    const float* __restrict__ bq, const float* __restrict__ bk, const float* __restrict__ bv,
    const float* __restrict__ Wo,
    _Float16* __restrict__ xh, _Float16* __restrict__ wqkvT, _Float16* __restrict__ woT,
    float* __restrict__ bqkv)
{
    long i0 = (long)blockIdx.x * blockDim.x + threadIdx.x;
    long stride = (long)gridDim.x * blockDim.x;
    const long NX  = (long)ROWS_ * D_;
    const long NW  = (long)D_ * NQKV_;
    const long NWO = (long)D_ * D_;

    for (long i = i0; i < NX; i += stride) xh[i] = (_Float16)x[i];

    for (long i = i0; i < NW; i += stride) {
        long n = i >> 9, k = i & 511;
        long which = n >> 9, nn = n & 511;
        const float* W = (which == 0) ? Wq : (which == 1) ? Wk : Wv;
        wqkvT[i] = (_Float16)W[k * 512 + nn];
    }
    for (long i = i0; i < NWO; i += stride) {
        long n = i >> 9, k = i & 511;
        woT[i] = (_Float16)Wo[k * 512 + n];
    }
    for (long i = i0; i < NQKV_; i += stride) {
        long which = i >> 9, nn = i & 511;
        const float* bb = (which == 0) ? bq : (which == 1) ? bk : bv;
        bqkv[i] = bb[nn];
    }
}

// ------------------------------------------------------------------- GEMM ---
#define GP 40
template <bool OUT_F16>
__global__ __launch_bounds__(256) void gemm_bt(
    const _Float16* __restrict__ A, const _Float16* __restrict__ BT,
    const float* __restrict__ bias, void* __restrict__ Cout,
    int M, int N, int K)
{
    __shared__ _Float16 As[128 * GP];
    __shared__ _Float16 Bs[128 * GP];

    int tid = threadIdx.x;
    int w = tid >> 6, lane = tid & 63, quad = lane >> 4, l16 = lane & 15;
    long row0 = (long)blockIdx.x * 128, col0 = (long)blockIdx.y * 128;
    int wr = (w >> 1) * 64, wc = (w & 1) * 64;

    f4 acc[4][4];
    for (int i = 0; i < 4; i++)
        for (int j = 0; j < 4; j++) acc[i][j] = (f4){0.f, 0.f, 0.f, 0.f};

    int sr = tid >> 1, sc = (tid & 1) * 16;
    for (int k0 = 0; k0 < K; k0 += 32) {
        __syncthreads();
        {
            const h8* ga = (const h8*)(A  + (row0 + sr) * K + k0 + sc);
            const h8* gb = (const h8*)(BT + (col0 + sr) * K + k0 + sc);
            *(h8*)(As + sr * GP + sc)     = ga[0];
            *(h8*)(As + sr * GP + sc + 8) = ga[1];
            *(h8*)(Bs + sr * GP + sc)     = gb[0];
            *(h8*)(Bs + sr * GP + sc + 8) = gb[1];
        }
        __syncthreads();
        h8 af[4], bf[4];
        for (int i = 0; i < 4; i++) af[i] = *(const h8*)(As + (wr + i * 16 + l16) * GP + quad * 8);
        for (int j = 0; j < 4; j++) bf[j] = *(const h8*)(Bs + (wc + j * 16 + l16) * GP + quad * 8);
        for (int i = 0; i < 4; i++)
            for (int j = 0; j < 4; j++)
                acc[i][j] = __builtin_amdgcn_mfma_f32_16x16x32_f16(af[i], bf[j], acc[i][j], 0, 0, 0);
    }
    for (int i = 0; i < 4; i++)
        for (int j = 0; j < 4; j++)
            for (int r = 0; r < 4; r++) {
                long row = row0 + wr + i * 16 + quad * 4 + r;
                long col = col0 + wc + j * 16 + l16;
                float v = acc[i][j][r] + bias[col];
                if (OUT_F16) ((_Float16*)Cout)[row * N + col] = (_Float16)v;
                else         ((float*)Cout)[row * N + col]    = v;
            }
}

// ---------------------------------------------------------------- pack V ---
// vP fragment-major layout: for batch b, key-tile kt (32 keys), d-tile dt
// (16 d), the 16x32 tile is stored as 512 contiguous bf16:
//   vP[(((b*128)+kt)*32+dt)*512 + (q*16+l)*8 + k3] = V[b][kt*32+q*8+k3][dt*16+l]
// so an MFMA B-fragment load is lane*16B off a wave-uniform base.
__global__ __launch_bounds__(256) void pack_v(const _Float16* __restrict__ qkv,
                                              __bf16* __restrict__ vP)
{
    __shared__ _Float16 T[32 * 520];
    int kt = blockIdx.x, b = blockIdx.y;
    int t = threadIdx.x;

    // coalesced load: 32 keys x 512 d (f16) from qkv[.][1024+..]
    const _Float16* src = qkv + ((long)b * S_ + kt * 32 + (t >> 3)) * NQKV_ + 1024;
#pragma unroll
    for (int i = 0; i < 8; i++) {
        int c = (t & 7) + i * 8;                     // chunk 0..63 within row
        *(h8*)(T + (t >> 3) * 520 + c * 8) = *(const h8*)(src + c * 8);
    }
    __syncthreads();

    // coalesced store: 2048 chunks of 8 bf16; chunk c -> dt=c>>6, q=(c>>4)&3, l=c&15
    __bf16* dst = vP + (((long)b * 128 + kt) * 32) * 512;
#pragma unroll
    for (int i = 0; i < 8; i++) {
        int c = t + i * 256;
        int dt = c >> 6, q = (c >> 4) & 3, l = c & 15;
        b8 out;
#pragma unroll
        for (int k3 = 0; k3 < 8; k3++)
            out[k3] = (__bf16)(float)T[(q * 8 + k3) * 520 + dt * 16 + l];
        *(b8*)(dst + (long)c * 8) = out;
    }
}

// -------------------------------------------------------- flash attention ---
// BR=64, BC=32, 8 waves (512 thr), 256 blocks (1/CU), XCD batch affinity.
// PRODUCER/CONSUMER WAVE SPECIALIZATION (two disjoint loops so the role live
// sets do NOT union -> no spill, unlike R6):
//   waves 0-3 (producers): rows (w&1)*32..+31 (Qf[2][16]=128 VGPR), keys
//     (w>>1)*16..+15.  Each kb fragment read from LDS feeds TWO row-tile
//     MFMAs -> kb LDS traffic halves (128->64 KB/iter/CU).  Compute scores
//     + exp, write Ps, accumulate l.  No O, no V.
//   waves 4-7 (consumers): all 64 rows x d-range (w-4)*128 (O[4][8]=128
//     VGPR, vA/vB=64).  Read pa (halved: 4 waves not 8), V from vP, MFMA
//     into O, write yb.  No Qf, never read Ks.
// Per inter-barrier region: producer scores(kt+1) runs CONCURRENTLY with
// consumer PV(kt) (Ps double-buffered).  Barrier counts per role are equal
// (1 prologue + 128 loop + 1 epilogue).  Counted vmcnt per role:
//   producers: region = 4 K-DMA -> vmcnt(4)  (tail 0)
//   consumers: region = 8 V + 4 K-DMA -> vmcnt(12)  (tails 8/0)
// Both retire DMA(kt+1) at barrier(kt) -> Ks visible for scores(kt+1).
// K-DMA: wave w stages rows w*4..w*4+3 (producers 0-15, consumers 16-31).
__global__ __launch_bounds__(512, 2) void attn_kernel(const _Float16* __restrict__ qkv,
                                                      const __bf16* __restrict__ vP,
                                                      _Float16* __restrict__ yb)
{
    __shared__ _Float16 Ks[4 * KTILE];      // 133120 B
    __shared__ __bf16   Ps[2 * BR * PP];    // 10240 B
    __shared__ float    lpart[2][BR];       // 512 B

    const int tid = threadIdx.x;
    const int w = tid >> 6, lane = tid & 63, quad = lane >> 4, l16 = lane & 15;

    // ---- batch->XCD affinity swizzle (bijective over 256 blocks)
    const int bid = blockIdx.x;
    const int xcd = bid & 7;
    const int b = xcd >> 1;
    const long q0 = (long)((xcd & 1) * 32 + (bid >> 3)) * BR;
    const long rowBase = (long)b * S_;

    const _Float16* kbase = qkv + rowBase * NQKV_ + 512;

    if (w < 4) {
        // ==================================================== PRODUCER ====
        const int rs0 = (w & 1) * 32;       // first row of this wave's strip
        const int kh  = w >> 1;             // key 16-group (0/1)

        h8 Qf0[16], Qf1[16];
        {
            const _Float16* q0p = qkv + (rowBase + q0 + rs0 + l16) * NQKV_;
            const _Float16* q1p = qkv + (rowBase + q0 + rs0 + 16 + l16) * NQKV_;
#pragma unroll
            for (int ks = 0; ks < 16; ks++) {
                Qf0[ks] = *(const h8*)(q0p + ks * 32 + quad * 8);
                Qf1[ks] = *(const h8*)(q1p + ks * 32 + quad * 8);
            }
        }
#pragma unroll
        for (int t = 0; t < 2; t++)
#pragma unroll
            for (int i = 0; i < 4; i++) {
                int r = w * 4 + i;
                gl_lds16(kbase + (long)(t * BC + r) * NQKV_ + lane * 8,
                         Ks + t * KTILE + r * KP);
            }
        float lo0[4] = {0.f, 0.f, 0.f, 0.f};
        float lo1[4] = {0.f, 0.f, 0.f, 0.f};

        __syncthreads();    // prologue barrier (full drain: K0,K1 landed)

        for (int kt = 0; kt < NIT; kt++) {
            if (kt + 2 < NIT) {
                const _Float16* kn = kbase + (long)(kt + 2) * BC * NQKV_;
                _Float16* kd = Ks + ((kt + 2) & 3) * KTILE;
#pragma unroll
                for (int i = 0; i < 4; i++) {
                    int r = w * 4 + i;
                    gl_lds16(kn + (long)r * NQKV_ + lane * 8, kd + r * KP);
                }
            }
            f4 Sa0 = (f4){0.f, 0.f, 0.f, 0.f}, Sa1 = (f4){0.f, 0.f, 0.f, 0.f};
            f4 Sb0 = (f4){0.f, 0.f, 0.f, 0.f}, Sb1 = (f4){0.f, 0.f, 0.f, 0.f};
            const _Float16* krow = Ks + (kt & 3) * KTILE + (kh * 16 + l16) * KP + quad * 8;
            __builtin_amdgcn_s_setprio(1);
#pragma unroll
            for (int ks = 0; ks < 8; ks++) {
                h8 kb0 = *(const h8*)(krow + ks * 32);
                h8 kb1 = *(const h8*)(krow + (ks + 8) * 32);
                Sa0 = __builtin_amdgcn_mfma_f32_16x16x32_f16(Qf0[ks],     kb0, Sa0, 0, 0, 0);
                Sb0 = __builtin_amdgcn_mfma_f32_16x16x32_f16(Qf1[ks],     kb0, Sb0, 0, 0, 0);
                Sa1 = __builtin_amdgcn_mfma_f32_16x16x32_f16(Qf0[ks + 8], kb1, Sa1, 0, 0, 0);
                Sb1 = __builtin_amdgcn_mfma_f32_16x16x32_f16(Qf1[ks + 8], kb1, Sb1, 0, 0, 0);
            }
            __builtin_amdgcn_s_setprio(0);
            __bf16* ps = Ps + (kt & 1) * (BR * PP);
#pragma unroll
            for (int r = 0; r < 4; r++) {
                float p0 = exp2f((Sa0[r] + Sa1[r]) * L2E - MSH);
                float p1 = exp2f((Sb0[r] + Sb1[r]) * L2E - MSH);
                __bf16 pb0 = (__bf16)p0, pb1 = (__bf16)p1;
                ps[(rs0 + quad * 4 + r) * PP + kh * 16 + l16] = pb0;
                ps[(rs0 + 16 + quad * 4 + r) * PP + kh * 16 + l16] = pb1;
                lo0[r] += (float)pb0;
                lo1[r] += (float)pb1;
            }
            __builtin_amdgcn_sched_barrier(0);
            if (kt < NIT - 2) asm volatile("s_waitcnt vmcnt(4)");
            else              asm volatile("s_waitcnt vmcnt(0)");
            asm volatile("s_waitcnt lgkmcnt(0)");
            __builtin_amdgcn_s_barrier();
            __builtin_amdgcn_sched_barrier(0);
        }

        // epilogue: reduce l over the 16 key lanes, publish per key-group
#pragma unroll
        for (int r = 0; r < 4; r++)
#pragma unroll
            for (int m = 1; m < 16; m <<= 1) {
                lo0[r] += __shfl_xor(lo0[r], m, 16);
                lo1[r] += __shfl_xor(lo1[r], m, 16);
            }
        if (l16 == 0)
            for (int r = 0; r < 4; r++) {
                lpart[kh][rs0 + quad * 4 + r]      = lo0[r];
                lpart[kh][rs0 + 16 + quad * 4 + r] = lo1[r];
            }
        __syncthreads();    // epilogue barrier (publishes lpart)
        // producers write no output
    } else {
        // ==================================================== CONSUMER ====
        const int cv = w - 4;               // d-range cv*128 .. cv*128+127
        const __bf16* vpbase = vP + ((long)b * 128 * 32 + cv * 8) * 512 + lane * 8;

#pragma unroll
        for (int t = 0; t < 2; t++)
#pragma unroll
            for (int i = 0; i < 4; i++) {
                int r = w * 4 + i;
                gl_lds16(kbase + (long)(t * BC + r) * NQKV_ + lane * 8,
                         Ks + t * KTILE + r * KP);
            }
        b8 vA[8], vB[8];
#pragma unroll
        for (int ct = 0; ct < 8; ct++)
            vA[ct] = *(const b8*)(vpbase + ct * 512);

        f4 O[4][8];
#pragma unroll
        for (int rt = 0; rt < 4; rt++)
#pragma unroll
            for (int ct = 0; ct < 8; ct++) O[rt][ct] = (f4){0.f, 0.f, 0.f, 0.f};

        __syncthreads();    // prologue barrier

#define CONS_BODY(KT, VUSE, VLOAD)                                              \
  {                                                                             \
    const int kt_ = (KT);                                                       \
    if (kt_ + 1 < NIT) {                                                        \
      const __bf16* vs = vpbase + (long)(kt_ + 1) * (32 * 512);                 \
      _Pragma("unroll")                                                         \
      for (int ct = 0; ct < 8; ct++)                                            \
        VLOAD[ct] = *(const b8*)(vs + ct * 512);                                \
    }                                                                           \
    if (kt_ + 2 < NIT) {                                                        \
      const _Float16* kn = kbase + (long)(kt_ + 2) * BC * NQKV_;                \
      _Float16* kd = Ks + ((kt_ + 2) & 3) * KTILE;                              \
      _Pragma("unroll")                                                         \
      for (int i = 0; i < 4; i++) {                                             \
        int r = w * 4 + i;                                                      \
        gl_lds16(kn + (long)r * NQKV_ + lane * 8, kd + r * KP);                 \
      }                                                                         \
    }                                                                           \
    __builtin_amdgcn_sched_barrier(0);                                          \
    if (kt_ < NIT - 2)       asm volatile("s_waitcnt vmcnt(12)");               \
    else if (kt_ == NIT - 2) asm volatile("s_waitcnt vmcnt(8)");                \
    else                     asm volatile("s_waitcnt vmcnt(0)");                \
    asm volatile("s_waitcnt lgkmcnt(0)");                                       \
    __builtin_amdgcn_s_barrier();                                               \
    __builtin_amdgcn_sched_barrier(0);                                          \
    const __bf16* ps = Ps + (kt_ & 1) * (BR * PP);                              \
    b8 pa[4];                                                                   \
    _Pragma("unroll")                                                           \
    for (int rt = 0; rt < 4; rt++)                                              \
      pa[rt] = *(const b8*)(ps + (rt * 16 + l16) * PP + quad * 8);              \
    __builtin_amdgcn_s_setprio(1);                                              \
    _Pragma("unroll")                                                           \
    for (int ct = 0; ct < 8; ct++)                                              \
      _Pragma("unroll")                                                         \
      for (int rt = 0; rt < 4; rt++)                                            \
        O[rt][ct] = __builtin_amdgcn_mfma_f32_16x16x32_bf16(pa[rt], VUSE[ct], O[rt][ct], 0, 0, 0); \
    __builtin_amdgcn_s_setprio(0);                                              \
  }

        for (int kt = 0; kt < NIT; kt += 2) {
            CONS_BODY(kt,     vA, vB);
            CONS_BODY(kt + 1, vB, vA);
        }
#undef CONS_BODY

        __syncthreads();    // epilogue barrier (lpart visible)

#pragma unroll
        for (int rt = 0; rt < 4; rt++) {
            f4 l0 = *(const f4*)(&lpart[0][rt * 16 + quad * 4]);
            f4 l1 = *(const f4*)(&lpart[1][rt * 16 + quad * 4]);
            float li[4];
            for (int r = 0; r < 4; r++) li[r] = 1.f / (l0[r] + l1[r]);
            for (int ct = 0; ct < 8; ct++)
                for (int r = 0; r < 4; r++) {
                    long row = rowBase + q0 + rt * 16 + quad * 4 + r;
                    long col = cv * 128 + ct * 16 + l16;
                    yb[row * 512 + col] = (_Float16)(O[rt][ct][r] * li[r]);
                }
        }
    }
}

// ----------------------------------------------------------------- launch ---
extern "C" void kernel_launch(void* const* d_in, const int* in_sizes, int n_in,
                              void* d_out, int out_size, void* d_ws, size_t ws_size,
                              hipStream_t stream)
{
    const float* x  = (const float*)d_in[0];
    const float* Wq = (const float*)d_in[1];
    const float* bq = (const float*)d_in[2];
    const float* Wk = (const float*)d_in[3];
    const float* bk = (const float*)d_in[4];
    const float* Wv = (const float*)d_in[5];
    const float* bv = (const float*)d_in[6];
    const float* Wo = (const float*)d_in[7];
    const float* bo = (const float*)d_in[8];
    float* out = (float*)d_out;

    char* ws = (char*)d_ws;
    _Float16* xh    = (_Float16*)(ws);                  // 16 MB
    _Float16* qkv   = (_Float16*)(ws + 16777216);       // 48 MB  [16384][1536]
    __bf16*   vP    = (__bf16*)(ws + 67108864);         // 16 MB  packed V
    _Float16* yb    = (_Float16*)(ws + 83886080);       // 16 MB  [16384][512]
    _Float16* wqkvT = (_Float16*)(ws + 100663296);      // 1.5 MB
    _Float16* woT   = (_Float16*)(ws + 102236160);      // 0.5 MB
    float*    bqkv  = (float*)(ws + 102760448);         // 6 KB

    convert_all<<<2048, 256, 0, stream>>>(x, Wq, Wk, Wv, bq, bk, bv, Wo,
                                          xh, wqkvT, woT, bqkv);

    dim3 g1(128, 12);
    gemm_bt<true><<<g1, 256, 0, stream>>>(xh, wqkvT, bqkv, qkv, ROWS_, NQKV_, D_);

    dim3 gp(128, 4);
    pack_v<<<gp, 256, 0, stream>>>(qkv, vP);

    attn_kernel<<<256, 512, 0, stream>>>(qkv, vP, yb);

    dim3 g2(128, 4);
    gemm_bt<false><<<g2, 256, 0, stream>>>(yb, woT, bo, out, ROWS_, D_, D_);
}